// Round 14
// baseline (34.419 us; speedup 1.0000x reference)
//
#include <hip/hip_runtime.h>

#define IW 4096
#define OH 4094
#define OW 4094
#define NWG 512              // 2 blocks/CU; 4 waves/block -> 2048 waves
#define XCHUNK 64            // NWG / 8
#define STEPS 8              // 8 x 256 cols = 2048 cols per wave (half a row)

typedef float f32x4 __attribute__((ext_vector_type(4)));
typedef float f32x2 __attribute__((ext_vector_type(2)));

__global__ __launch_bounds__(256) void conv3x3_sweep(
    const float* __restrict__ in, const float* __restrict__ wgt,
    const float* __restrict__ bias, float* __restrict__ out) {

    // XCD-aware bijective swizzle (512 % 8 == 0): each XCD gets a
    // contiguous 512-row band (64 blocks -> 128 row-groups).
    int b   = blockIdx.x;
    int swz = (b & 7) * XCHUNK + (b >> 3);

    int lane  = (int)threadIdx.x & 63;
    int wib   = (int)threadIdx.x >> 6;        // wave in block, 0..3
    int wid   = swz * 4 + wib;                // global wave id, 0..2047
    int rg    = wid >> 1;                     // row-group 0..1023 (4 rows each)
    int half  = wid & 1;                      // which 2048-col half
    int row0  = rg << 2;                      // output row start (even)

    float wv[9];
#pragma unroll
    for (int i = 0; i < 9; ++i) wv[i] = wgt[i];
    float bs = bias[0];

    int nr    = (row0 + 4 <= OH) ? 4 : (OH - row0);  // wave-uniform: 4, or 2 at rg==1023
    int nload = nr + 2;

    int xbase = half * 2048 + lane * 4;

    // Horizontal sweep: each wave advances 256 cols/step, so every one of its
    // 4 output-row store streams (and 6 input-row load streams) is SEQUENTIAL
    // in memory across steps -> long DRAM page-hit runs, like the fill kernel.
    for (int s = 0; s < STEPS; ++s) {
        int x = xbase + s * 256;              // output col start (multiple of 4)

        float r[6][6];
#pragma unroll
        for (int t = 0; t < 6; ++t) {
            if (t < nload) {                                   // wave-uniform
                const float* rp = in + (size_t)(row0 + t) * IW + x;
                f32x4 a = *reinterpret_cast<const f32x4*>(rp); // 16B-aligned
                r[t][0] = a[0]; r[t][1] = a[1]; r[t][2] = a[2]; r[t][3] = a[3];
                if (x + 5 < IW) {                              // false only at x==4092
                    f32x2 e = *reinterpret_cast<const f32x2*>(rp + 4);
                    r[t][4] = e[0]; r[t][5] = e[1];
                } else { r[t][4] = 0.f; r[t][5] = 0.f; }
            } else {
#pragma unroll
                for (int j = 0; j < 6; ++j) r[t][j] = 0.f;
            }
        }

        float acc[4][4];
#pragma unroll
        for (int i = 0; i < 4; ++i)
#pragma unroll
            for (int c = 0; c < 4; ++c) acc[i][c] = bs;

#pragma unroll
        for (int orow = 0; orow < 4; ++orow) {
#pragma unroll
            for (int kh = 0; kh < 3; ++kh) {
                int t = orow + kh;
                float w0 = wv[kh * 3 + 0], w1 = wv[kh * 3 + 1], w2 = wv[kh * 3 + 2];
#pragma unroll
                for (int c = 0; c < 4; ++c)
                    acc[orow][c] += w0 * r[t][c] + w1 * r[t][c + 1] + w2 * r[t][c + 2];
            }
        }

        // R9-proven store pattern, NT (R12 A/B: NT is +7%).
        int nc = (x + 4 <= OW) ? 4 : (OW - x);       // 4, or 2 at x==4092
#pragma unroll
        for (int orow = 0; orow < 4; ++orow) {
            if (orow < nr) {                          // wave-uniform
                float* op = out + (size_t)(row0 + orow) * OW + x;
                if (nc == 4) {
                    if ((orow & 1) == 0) {
                        f32x4 v = { acc[orow][0], acc[orow][1],
                                    acc[orow][2], acc[orow][3] };
                        __builtin_nontemporal_store(v, reinterpret_cast<f32x4*>(op));
                    } else {
                        f32x2 v0 = { acc[orow][0], acc[orow][1] };
                        f32x2 v1 = { acc[orow][2], acc[orow][3] };
                        __builtin_nontemporal_store(v0, reinterpret_cast<f32x2*>(op));
                        __builtin_nontemporal_store(v1, reinterpret_cast<f32x2*>(op + 2));
                    }
                } else {
                    f32x2 v0 = { acc[orow][0], acc[orow][1] };
                    __builtin_nontemporal_store(v0, reinterpret_cast<f32x2*>(op));
                }
            }
        }
    }
}

extern "C" void kernel_launch(void* const* d_in, const int* in_sizes, int n_in,
                              void* d_out, int out_size, void* d_ws, size_t ws_size,
                              hipStream_t stream) {
    const float* in   = (const float*)d_in[0];
    const float* wgt  = (const float*)d_in[1];
    const float* bias = (const float*)d_in[2];
    float* out        = (float*)d_out;

    conv3x3_sweep<<<NWG, 256, 0, stream>>>(in, wgt, bias, out);
}

// Round 15
// 30.963 us; speedup vs baseline: 1.1116x; 1.1116x over previous
//
#include <hip/hip_runtime.h>

#define IW 4096
#define OH 4094
#define OW 4094
#define NWG 2048             // 8192 waves: 8 wave-cols x 1024 row-groups
#define XCHUNK 256           // NWG / 8

typedef float f32x4 __attribute__((ext_vector_type(4)));
typedef float f32x2 __attribute__((ext_vector_type(2)));

__global__ __launch_bounds__(256) void conv3x3_dual(
    const float* __restrict__ in, const float* __restrict__ wgt,
    const float* __restrict__ bias, float* __restrict__ out) {

    // XCD-aware bijective swizzle (2048 % 8 == 0).
    int b    = blockIdx.x;
    int swz  = (b & 7) * XCHUNK + (b >> 3);
    int lane = (int)threadIdx.x & 63;
    int wib  = (int)threadIdx.x >> 6;

    int wid  = swz * 4 + wib;      // global wave id 0..8191
    int wc   = wid & 7;            // wave-col: 512-float span
    int rg   = wid >> 3;           // row-group 0..1023
    int row0 = rg << 2;            // output row start (even)

    int x0 = wc * 512 + lane * 4;  // strip 0 col (<= 3836: tails unguarded)
    int x1 = x0 + 256;             // strip 1 col (<= 4092: tail guarded)

    float wv[9];
#pragma unroll
    for (int i = 0; i < 9; ++i) wv[i] = wgt[i];
    float bs = bias[0];

    int nr    = (row0 + 4 <= OH) ? 4 : (OH - row0);  // wave-uniform: 4, or 2 at rg==1023
    int nload = nr + 2;

    // Dual-strip loads: per row, two aligned f32x4 (each a contiguous 1KB wave
    // access) + two f32x2 tails. 12 independent b128 loads in flight per wave.
    float r0[6][6], r1[6][6];
#pragma unroll
    for (int t = 0; t < 6; ++t) {
        if (t < nload) {                                     // wave-uniform
            const float* rp = in + (size_t)(row0 + t) * IW;
            f32x4 a0 = *reinterpret_cast<const f32x4*>(rp + x0);
            f32x4 a1 = *reinterpret_cast<const f32x4*>(rp + x1);
            f32x2 e0 = *reinterpret_cast<const f32x2*>(rp + x0 + 4);  // always in-bounds
            float e1a = 0.f, e1b = 0.f;
            if (x1 + 5 < IW) {                               // false only wc==7,lane==63
                f32x2 e1 = *reinterpret_cast<const f32x2*>(rp + x1 + 4);
                e1a = e1[0]; e1b = e1[1];
            }
            r0[t][0]=a0[0]; r0[t][1]=a0[1]; r0[t][2]=a0[2]; r0[t][3]=a0[3];
            r0[t][4]=e0[0]; r0[t][5]=e0[1];
            r1[t][0]=a1[0]; r1[t][1]=a1[1]; r1[t][2]=a1[2]; r1[t][3]=a1[3];
            r1[t][4]=e1a;   r1[t][5]=e1b;
        } else {
#pragma unroll
            for (int j = 0; j < 6; ++j) { r0[t][j] = 0.f; r1[t][j] = 0.f; }
        }
    }

    float acc0[4][4], acc1[4][4];
#pragma unroll
    for (int i = 0; i < 4; ++i)
#pragma unroll
        for (int c = 0; c < 4; ++c) { acc0[i][c] = bs; acc1[i][c] = bs; }

#pragma unroll
    for (int orow = 0; orow < 4; ++orow) {
#pragma unroll
        for (int kh = 0; kh < 3; ++kh) {
            int t = orow + kh;
            float w0 = wv[kh*3+0], w1 = wv[kh*3+1], w2 = wv[kh*3+2];
#pragma unroll
            for (int c = 0; c < 4; ++c) {
                acc0[orow][c] += w0*r0[t][c] + w1*r0[t][c+1] + w2*r0[t][c+2];
                acc1[orow][c] += w0*r1[t][c] + w1*r1[t][c+1] + w2*r1[t][c+2];
            }
        }
    }

    // Stores (NT, R9-proven per-row pattern; every instr contiguous across wave).
    int nc1 = (x1 + 4 <= OW) ? 4 : (OW - x1);   // 4, or 2 at x1==4092
#pragma unroll
    for (int orow = 0; orow < 4; ++orow) {
        if (orow < nr) {                         // wave-uniform
            float* op0 = out + (size_t)(row0 + orow) * OW + x0;
            float* op1 = out + (size_t)(row0 + orow) * OW + x1;
            if ((orow & 1) == 0) {
                f32x4 v = { acc0[orow][0], acc0[orow][1], acc0[orow][2], acc0[orow][3] };
                __builtin_nontemporal_store(v, reinterpret_cast<f32x4*>(op0));
                if (nc1 == 4) {
                    f32x4 u = { acc1[orow][0], acc1[orow][1], acc1[orow][2], acc1[orow][3] };
                    __builtin_nontemporal_store(u, reinterpret_cast<f32x4*>(op1));
                } else {
                    f32x2 u = { acc1[orow][0], acc1[orow][1] };
                    __builtin_nontemporal_store(u, reinterpret_cast<f32x2*>(op1));
                }
            } else {
                f32x2 v0 = { acc0[orow][0], acc0[orow][1] };
                f32x2 v1 = { acc0[orow][2], acc0[orow][3] };
                __builtin_nontemporal_store(v0, reinterpret_cast<f32x2*>(op0));
                __builtin_nontemporal_store(v1, reinterpret_cast<f32x2*>(op0 + 2));
                f32x2 u0 = { acc1[orow][0], acc1[orow][1] };
                __builtin_nontemporal_store(u0, reinterpret_cast<f32x2*>(op1));
                if (nc1 == 4) {
                    f32x2 u1 = { acc1[orow][2], acc1[orow][3] };
                    __builtin_nontemporal_store(u1, reinterpret_cast<f32x2*>(op1 + 2));
                }
            }
        }
    }
}

extern "C" void kernel_launch(void* const* d_in, const int* in_sizes, int n_in,
                              void* d_out, int out_size, void* d_ws, size_t ws_size,
                              hipStream_t stream) {
    const float* in   = (const float*)d_in[0];
    const float* wgt  = (const float*)d_in[1];
    const float* bias = (const float*)d_in[2];
    float* out        = (float*)d_out;

    conv3x3_dual<<<NWG, 256, 0, stream>>>(in, wgt, bias, out);
}

// Round 16
// 30.434 us; speedup vs baseline: 1.1309x; 1.0174x over previous
//
#include <hip/hip_runtime.h>

#define IW 4096
#define OH 4094
#define OW 4094
#define CG 1024              // col-groups per row (4 cols each)
#define NWG 4096             // (1024 * 1024) / 256

typedef float f32x4 __attribute__((ext_vector_type(4)));
typedef float f32x2 __attribute__((ext_vector_type(2)));

__global__ __launch_bounds__(256) void conv3x3_nosw(
    const float* __restrict__ in, const float* __restrict__ wgt,
    const float* __restrict__ bias, float* __restrict__ out) {

    // R9 kernel with LINEAR block order (no XCD swizzle) — single A/B variable.
    // FETCH_SIZE=33MB showed the input is L3-resident, so the swizzle's L2
    // read-locality benefit is moot; linear order gives denser write streams.
    int idx = (int)blockIdx.x * 256 + (int)threadIdx.x;

    int cg   = idx & (CG - 1);
    int rg   = idx >> 10;          // uniform within a block
    int x    = cg << 2;            // output col start (multiple of 4)
    int row0 = rg << 2;            // output row start (even)

    float wv[9];
#pragma unroll
    for (int i = 0; i < 9; ++i) wv[i] = wgt[i];
    float bs = bias[0];

    int nr    = (row0 + 4 <= OH) ? 4 : (OH - row0);  // 4, or 2 at rg==1023 (uniform)
    int nload = nr + 2;                              // input rows needed

    float r[6][6];
#pragma unroll
    for (int t = 0; t < 6; ++t) {
        if (t < nload) {
            const float* rp = in + (size_t)(row0 + t) * IW + x;
            f32x4 a = *reinterpret_cast<const f32x4*>(rp);   // 16B-aligned
            r[t][0] = a[0]; r[t][1] = a[1]; r[t][2] = a[2]; r[t][3] = a[3];
            if (x + 5 < IW) {                                // false only at x==4092
                f32x2 e = *reinterpret_cast<const f32x2*>(rp + 4);
                r[t][4] = e[0]; r[t][5] = e[1];
            } else { r[t][4] = 0.f; r[t][5] = 0.f; }
        } else {
#pragma unroll
            for (int j = 0; j < 6; ++j) r[t][j] = 0.f;
        }
    }

    float acc[4][4];
#pragma unroll
    for (int i = 0; i < 4; ++i)
#pragma unroll
        for (int c = 0; c < 4; ++c) acc[i][c] = bs;

#pragma unroll
    for (int orow = 0; orow < 4; ++orow) {
#pragma unroll
        for (int kh = 0; kh < 3; ++kh) {
            int t = orow + kh;
            float w0 = wv[kh * 3 + 0], w1 = wv[kh * 3 + 1], w2 = wv[kh * 3 + 2];
#pragma unroll
            for (int c = 0; c < 4; ++c)
                acc[orow][c] += w0 * r[t][c] + w1 * r[t][c + 1] + w2 * r[t][c + 2];
        }
    }

    // R9-proven NT store pattern.
    int nc = (x + 4 <= OW) ? 4 : (OW - x);           // 4, or 2 at x==4092
#pragma unroll
    for (int orow = 0; orow < 4; ++orow) {
        if (orow < nr) {
            float* op = out + (size_t)(row0 + orow) * OW + x;
            if (nc == 4) {
                if ((orow & 1) == 0) {
                    f32x4 v = { acc[orow][0], acc[orow][1],
                                acc[orow][2], acc[orow][3] };
                    __builtin_nontemporal_store(v, reinterpret_cast<f32x4*>(op));
                } else {
                    f32x2 v0 = { acc[orow][0], acc[orow][1] };
                    f32x2 v1 = { acc[orow][2], acc[orow][3] };
                    __builtin_nontemporal_store(v0, reinterpret_cast<f32x2*>(op));
                    __builtin_nontemporal_store(v1, reinterpret_cast<f32x2*>(op + 2));
                }
            } else {
                f32x2 v0 = { acc[orow][0], acc[orow][1] };
                __builtin_nontemporal_store(v0, reinterpret_cast<f32x2*>(op));
            }
        }
    }
}

extern "C" void kernel_launch(void* const* d_in, const int* in_sizes, int n_in,
                              void* d_out, int out_size, void* d_ws, size_t ws_size,
                              hipStream_t stream) {
    const float* in   = (const float*)d_in[0];
    const float* wgt  = (const float*)d_in[1];
    const float* bias = (const float*)d_in[2];
    float* out        = (float*)d_out;

    conv3x3_nosw<<<NWG, 256, 0, stream>>>(in, wgt, bias, out);
}

// Round 17
// 27.812 us; speedup vs baseline: 1.2376x; 1.0943x over previous
//
#include <hip/hip_runtime.h>

#define IW 4096
#define OH 4094
#define OW 4094
#define CG 1024              // col-groups per row (4 cols each)
#define NWG 4096             // (1024 * 1024) / 256
#define XCHUNK 512           // NWG / 8

typedef float f32x4 __attribute__((ext_vector_type(4)));
typedef float f32x2 __attribute__((ext_vector_type(2)));

// Final kernel (R9 config — best of 8 A/B'd variants, 27.8 us):
//  - 4x4 output tile/thread: loads 0.75 instr/output, 16B-aligned f32x4 + f32x2
//  - XCD-aware swizzle: +9% (FETCH 50->33 MB; L2 read locality, R16 A/B)
//  - nontemporal stores: +7% (R12 A/B)
//  - f32x4 even rows / 2x adjacent f32x2 odd rows: +12% vs scalar (R7->R9);
//    per-lane tile MUST equal store width (R10: 8-col lanes -> WRITE_SIZE +60%)
__global__ __launch_bounds__(256) void conv3x3_final(
    const float* __restrict__ in, const float* __restrict__ wgt,
    const float* __restrict__ bias, float* __restrict__ out) {

    int b   = blockIdx.x;
    int swz = (b & 7) * XCHUNK + (b >> 3);
    int idx = swz * 256 + (int)threadIdx.x;

    int cg   = idx & (CG - 1);
    int rg   = idx >> 10;          // uniform within a block
    int x    = cg << 2;            // output col start (multiple of 4)
    int row0 = rg << 2;            // output row start (even)

    float wv[9];
#pragma unroll
    for (int i = 0; i < 9; ++i) wv[i] = wgt[i];
    float bs = bias[0];

    int nr    = (row0 + 4 <= OH) ? 4 : (OH - row0);  // 4, or 2 at rg==1023 (uniform)
    int nload = nr + 2;                              // input rows needed

    float r[6][6];
#pragma unroll
    for (int t = 0; t < 6; ++t) {
        if (t < nload) {
            const float* rp = in + (size_t)(row0 + t) * IW + x;
            f32x4 a = *reinterpret_cast<const f32x4*>(rp);   // 16B-aligned
            r[t][0] = a[0]; r[t][1] = a[1]; r[t][2] = a[2]; r[t][3] = a[3];
            if (x + 5 < IW) {                                // false only at x==4092
                f32x2 e = *reinterpret_cast<const f32x2*>(rp + 4);
                r[t][4] = e[0]; r[t][5] = e[1];
            } else { r[t][4] = 0.f; r[t][5] = 0.f; }
        } else {
#pragma unroll
            for (int j = 0; j < 6; ++j) r[t][j] = 0.f;
        }
    }

    float acc[4][4];
#pragma unroll
    for (int i = 0; i < 4; ++i)
#pragma unroll
        for (int c = 0; c < 4; ++c) acc[i][c] = bs;

#pragma unroll
    for (int orow = 0; orow < 4; ++orow) {
#pragma unroll
        for (int kh = 0; kh < 3; ++kh) {
            int t = orow + kh;
            float w0 = wv[kh * 3 + 0], w1 = wv[kh * 3 + 1], w2 = wv[kh * 3 + 2];
#pragma unroll
            for (int c = 0; c < 4; ++c)
                acc[orow][c] += w0 * r[t][c] + w1 * r[t][c + 1] + w2 * r[t][c + 2];
        }
    }

    int nc = (x + 4 <= OW) ? 4 : (OW - x);           // 4, or 2 at x==4092
#pragma unroll
    for (int orow = 0; orow < 4; ++orow) {
        if (orow < nr) {
            float* op = out + (size_t)(row0 + orow) * OW + x;
            if (nc == 4) {
                if ((orow & 1) == 0) {
                    f32x4 v = { acc[orow][0], acc[orow][1],
                                acc[orow][2], acc[orow][3] };
                    __builtin_nontemporal_store(v, reinterpret_cast<f32x4*>(op));
                } else {
                    f32x2 v0 = { acc[orow][0], acc[orow][1] };
                    f32x2 v1 = { acc[orow][2], acc[orow][3] };
                    __builtin_nontemporal_store(v0, reinterpret_cast<f32x2*>(op));
                    __builtin_nontemporal_store(v1, reinterpret_cast<f32x2*>(op + 2));
                }
            } else {
                f32x2 v0 = { acc[orow][0], acc[orow][1] };
                __builtin_nontemporal_store(v0, reinterpret_cast<f32x2*>(op));
            }
        }
    }
}

extern "C" void kernel_launch(void* const* d_in, const int* in_sizes, int n_in,
                              void* d_out, int out_size, void* d_ws, size_t ws_size,
                              hipStream_t stream) {
    const float* in   = (const float*)d_in[0];
    const float* wgt  = (const float*)d_in[1];
    const float* bias = (const float*)d_in[2];
    float* out        = (float*)d_out;

    conv3x3_final<<<NWG, 256, 0, stream>>>(in, wgt, bias, out);
}